// Round 7
// baseline (2942.223 us; speedup 1.0000x reference)
//
#include <hip/hip_runtime.h>
#include <hip/hip_bf16.h>

#define NN 100000
#define EE 1000000
#define FIN 15
#define HH 64
#define EMBD 128
#define RR 13
#define NBASE 4
#define NP 391          // ceil(NN/256) scan blocks

typedef __hip_bfloat16 bf16;
typedef __attribute__((ext_vector_type(8))) short short8;   // MFMA A/B frag (8 bf16)
typedef __attribute__((ext_vector_type(4))) float f32x4;    // MFMA C/D frag

__device__ __forceinline__ float b2f(bf16 x) { return __bfloat162float(x); }
__device__ __forceinline__ float bcast(float v, int l) {
    return __uint_as_float(__builtin_amdgcn_readlane(__float_as_uint(v), l));
}
__device__ __forceinline__ unsigned short f2bu(float f) {
    bf16 t = __float2bfloat16(f);
    return *reinterpret_cast<unsigned short*>(&t);
}
__device__ __forceinline__ float bu2f(unsigned u) {
    return __uint_as_float(u << 16);
}

// ---------- dtype auto-detect ----------
__global__ void k_detect(const void* __restrict__ win, int* __restrict__ flag) {
    int tid = threadIdx.x;
    const bf16* p = (const bf16*)win;
    int cnt = 0;
    for (int i = tid; i < FIN * HH; i += 64) {
        float v = b2f(p[i]);
        if (!(fabsf(v) < 0.3f)) cnt++;
    }
#pragma unroll
    for (int off = 32; off > 0; off >>= 1) cnt += __shfl_down(cnt, off, 64);
    if (tid == 0) *flag = (cnt > 40) ? 1 : 0;
}

// ---------- fused convert ----------
struct ConvTab {
    const void* in[17];
    int n[17];
    int cum[18];
};

__global__ void k_convert_all(ConvTab tab, float* __restrict__ base,
                              const int* __restrict__ flag) {
    int g = blockIdx.x * 256 + threadIdx.x;
    if (g >= tab.cum[17]) return;
    int t = 0;
#pragma unroll
    for (int i = 0; i < 17; ++i) if (g >= tab.cum[i + 1]) t = i + 1;
    int local = g - tab.cum[t];
    if (local >= tab.n[t]) return;
    float v;
    if (*flag) v = ((const float*)tab.in[t])[local];
    else       v = b2f(((const bf16*)tab.in[t])[local]);
    base[g] = v;
}

// ---------- edge counting-sort by target ----------
__global__ void k_zero(int* __restrict__ a, int n) {
    int i = blockIdx.x * 256 + threadIdx.x;
    if (i < n) a[i] = 0;
}

__global__ void k_hist(const int* __restrict__ tgt, int* __restrict__ count,
                       int* __restrict__ rank) {
    int e = blockIdx.x * 256 + threadIdx.x;
    if (e >= EE) return;
    rank[e] = atomicAdd(&count[tgt[e]], 1);
}

__global__ void k_scan1(const int* __restrict__ count, int* __restrict__ scanned,
                        int* __restrict__ partials) {
    __shared__ int buf[256];
    int tid = threadIdx.x;
    int i = blockIdx.x * 256 + tid;
    int v = (i < NN) ? count[i] : 0;
    buf[tid] = v;
    __syncthreads();
    for (int off = 1; off < 256; off <<= 1) {
        int t = (tid >= off) ? buf[tid - off] : 0;
        __syncthreads();
        buf[tid] += t;
        __syncthreads();
    }
    if (i < NN) scanned[i] = buf[tid] - v;
    if (tid == 255) partials[blockIdx.x] = buf[255];
}

__global__ void k_scan2(int* __restrict__ partials) {
    __shared__ int buf[512];
    int tid = threadIdx.x;
    int v = (tid < NP) ? partials[tid] : 0;
    buf[tid] = v;
    __syncthreads();
    for (int off = 1; off < 512; off <<= 1) {
        int t = (tid >= off) ? buf[tid - off] : 0;
        __syncthreads();
        buf[tid] += t;
        __syncthreads();
    }
    if (tid < NP) partials[tid] = buf[tid] - v;
}

// packed word: src(17) | etype(4)<<17 | (tgt&15)<<21
__global__ void k_scatter(const int* __restrict__ src, const int* __restrict__ tgt,
                          const int* __restrict__ et, const int* __restrict__ rank,
                          const int* __restrict__ scanned, const int* __restrict__ partials,
                          int* __restrict__ packed) {
    int e = blockIdx.x * 256 + threadIdx.x;
    if (e >= EE) return;
    int t = tgt[e];
    int pos = scanned[t] + partials[t >> 8] + rank[e];
    packed[pos] = src[e] | (et[e] << 17) | ((t & 15) << 21);
}

// WcatT[n][k] bf16, k 0..255: bases[k>>6][k&63][n]; k 256..319: Wself[k-256][n]
__global__ void k_wcat(const float* __restrict__ bases0, const float* __restrict__ Wself0,
                       const float* __restrict__ bases1, const float* __restrict__ Wself1,
                       unsigned short* __restrict__ W0, unsigned short* __restrict__ W1) {
    int idx = blockIdx.x * 256 + threadIdx.x;
    if (idx >= HH * 320) return;
    int n = idx / 320, k = idx - n * 320;
    int b = k >> 6, kk = k & 63;
    float v0 = (b < 4) ? bases0[b * 4096 + kk * 64 + n] : Wself0[kk * 64 + n];
    float v1 = (b < 4) ? bases1[b * 4096 + kk * 64 + n] : Wself1[kk * 64 + n];
    W0[idx] = f2bu(v0);
    W1[idx] = f2bu(v1);
}

// ---------- pipeline (bf16 node state) ----------

__global__ void k_input_proj(const float* __restrict__ nf, const float* __restrict__ Win,
                             const float* __restrict__ bin, unsigned short* __restrict__ h) {
    __shared__ float w[FIN * HH];
    __shared__ float bb[HH];
    int tid = threadIdx.x;
    for (int i = tid; i < FIN * HH; i += 256) w[i] = Win[i];
    if (tid < HH) bb[tid] = bin[tid];
    __syncthreads();
    int idx = blockIdx.x * 256 + tid;
    if (idx >= NN * HH) return;
    int n = idx >> 6, j = idx & 63;
    float acc = bb[j];
    const float* row = nf + n * FIN;
#pragma unroll
    for (int k = 0; k < FIN; ++k) acc = fmaf(row[k], w[k * HH + j], acc);
    h[idx] = f2bu(acc);
}

// Fused RGCN layer, 16 nodes/block:
//  phase 1: edge-parallel gather S_b[loc][j] += c_r[b]*h[src][j] via ds_add_f32
//           (one edge per HALF-wave: 32 lanes x ushort2 cover the 64-wide row)
//  phase 2: MFMA tail  out = relu([S|h] @ WcatT^T + bself)
__global__ void __launch_bounds__(256, 4)
k_layer(const unsigned short* __restrict__ hin, const int* __restrict__ packed,
        const int* __restrict__ scanned, const int* __restrict__ partials,
        const float* __restrict__ coeffs, const unsigned short* __restrict__ Wc,
        const float* __restrict__ bself, unsigned short* __restrict__ hout) {
    __shared__ float Sacc[16 * 256];
    __shared__ __align__(16) unsigned short Sb[16 * 264];   // row stride 264 (16B-aligned)
    int tid = threadIdx.x;
    int t0 = blockIdx.x * 16;

    for (int i = tid; i < 16 * 256; i += 256) Sacc[i] = 0.f;
    __syncthreads();

    int eb0 = scanned[t0] + partials[t0 >> 8];
    int t1 = t0 + 16;
    int eb1 = (t1 >= NN) ? EE : (scanned[t1] + partials[t1 >> 8]);

    int hw = tid >> 5;        // 8 half-waves per block
    int l32 = tid & 31;
    for (int e = eb0 + hw; e < eb1; e += 8) {
        unsigned pk = (unsigned)packed[e];
        int s   = pk & 0x1FFFF;
        int r   = (pk >> 17) & 0xF;
        int loc = (pk >> 21) & 0xF;
        unsigned hv = *(const unsigned*)(hin + s * HH + l32 * 2);  // 2 bf16 feats
        float f0 = bu2f(hv & 0xFFFFu);
        float f1 = bu2f(hv >> 16);
        float4 c = *(const float4*)(coeffs + r * NBASE);
        float* srow = &Sacc[loc * 256 + l32 * 2];
        atomicAdd(&srow[0],   c.x * f0);  atomicAdd(&srow[1],   c.x * f1);
        atomicAdd(&srow[64],  c.y * f0);  atomicAdd(&srow[65],  c.y * f1);
        atomicAdd(&srow[128], c.z * f0);  atomicAdd(&srow[129], c.z * f1);
        atomicAdd(&srow[192], c.w * f0);  atomicAdd(&srow[193], c.w * f1);
    }
    __syncthreads();

    // fp32 -> bf16 (pairs)
    for (int i = tid; i < 2048; i += 256) {
        int loc = i >> 7, jp = (i & 127) * 2;
        unsigned pa = (unsigned)f2bu(Sacc[loc * 256 + jp])
                    | ((unsigned)f2bu(Sacc[loc * 256 + jp + 1]) << 16);
        *(unsigned*)&Sb[loc * 264 + jp] = pa;
    }
    __syncthreads();

    // MFMA: wave wv computes 16 nodes x cols [16wv,16wv+16)
    int wv = tid >> 6;
    int lane = tid & 63;
    int m16 = lane & 15;      // A: node row / B: output col
    int g = lane >> 4;        // k-group
    f32x4 acc = {0.f, 0.f, 0.f, 0.f};
    const unsigned short* brow = Wc + (wv * 16 + m16) * 320 + g * 8;
#pragma unroll
    for (int kb = 0; kb < 8; ++kb) {   // S part, K=256
        short8 a = *(const short8*)(&Sb[m16 * 264 + kb * 32 + g * 8]);
        short8 b = *(const short8*)(brow + kb * 32);
        acc = __builtin_amdgcn_mfma_f32_16x16x32_bf16(a, b, acc, 0, 0, 0);
    }
    const unsigned short* hrow = hin + (t0 + m16) * HH + g * 8;
#pragma unroll
    for (int kb = 0; kb < 2; ++kb) {   // self part, K=64
        short8 a = *(const short8*)(hrow + kb * 32);
        short8 b = *(const short8*)(brow + 256 + kb * 32);
        acc = __builtin_amdgcn_mfma_f32_16x16x32_bf16(a, b, acc, 0, 0, 0);
    }
    int col = wv * 16 + m16;
    float bias = bself[col];
#pragma unroll
    for (int r = 0; r < 4; ++r) {
        int row = g * 4 + r;
        hout[(t0 + row) * HH + col] = f2bu(fmaxf(acc[r] + bias, 0.f));
    }
}

// stage 1: per-block partial sum & max (h already relu'd)
__global__ void k_reduce(const unsigned short* __restrict__ h, float* __restrict__ psum,
                         float* __restrict__ pmax) {
    __shared__ float ls[256], lm[256];
    int tid = threadIdx.x;
    int j = tid & 63;
    int slot = tid >> 6;
    float s = 0.f, m = -1e30f;
    for (int n = blockIdx.x * 4 + slot; n < NN; n += gridDim.x * 4) {
        float v = bu2f(h[n * HH + j]);
        s += v;
        m = fmaxf(m, v);
    }
    ls[tid] = s; lm[tid] = m;
    __syncthreads();
    if (tid < 64) {
        s = ls[tid] + ls[tid + 64] + ls[tid + 128] + ls[tid + 192];
        m = fmaxf(fmaxf(lm[tid], lm[tid + 64]), fmaxf(lm[tid + 128], lm[tid + 192]));
        psum[blockIdx.x * 64 + tid] = s;
        pmax[blockIdx.x * 64 + tid] = m;
    }
}

// stage 2 + readout MLP fused
__global__ void k_finish(const float* __restrict__ psum, const float* __restrict__ pmax,
                         const float* __restrict__ Wr1, const float* __restrict__ br1,
                         const float* __restrict__ Wr2, const float* __restrict__ br2,
                         void* __restrict__ out, const int* __restrict__ flag) {
    __shared__ float ls[256], lm[256];
    __shared__ float g[2 * HH];
    __shared__ float tbuf[HH];
    int tid = threadIdx.x;
    int j = tid & 63;
    int slot = tid >> 6;
    float s = 0.f, m = -1e30f;
    for (int i = slot; i < 256; i += 4) {
        s += psum[i * 64 + j];
        m = fmaxf(m, pmax[i * 64 + j]);
    }
    ls[tid] = s; lm[tid] = m;
    __syncthreads();
    if (tid < 64) {
        s = ls[tid] + ls[tid + 64] + ls[tid + 128] + ls[tid + 192];
        m = fmaxf(fmaxf(lm[tid], lm[tid + 64]), fmaxf(lm[tid + 128], lm[tid + 192]));
        g[tid] = s * (1.0f / NN);
        g[64 + tid] = m;
    }
    __syncthreads();
    if (tid < 64) {
        float acc = br1[tid];
#pragma unroll 8
        for (int k = 0; k < 2 * HH; ++k) acc = fmaf(g[k], Wr1[k * HH + tid], acc);
        tbuf[tid] = fmaxf(acc, 0.f);
    }
    __syncthreads();
    if (tid < EMBD) {
        float acc = br2[tid];
#pragma unroll 8
        for (int k = 0; k < HH; ++k) acc = fmaf(tbuf[k], Wr2[k * EMBD + tid], acc);
        if (*flag) ((float*)out)[tid] = acc;
        else       ((bf16*)out)[tid] = __float2bfloat16(acc);
    }
}

// node_emb: 8 nodes/wave, 128 cols (2/lane)
__global__ void k_node_emb2(const unsigned short* __restrict__ h, const float* __restrict__ Wnp,
                            const float* __restrict__ bnp, void* __restrict__ out,
                            const int* __restrict__ flag) {
    int tid = threadIdx.x;
    int lane = tid & 63;
    int wv = tid >> 6;
    int n0 = blockIdx.x * 32 + wv * 8;
    float hval[8];
#pragma unroll
    for (int ln = 0; ln < 8; ++ln)
        hval[ln] = bu2f(h[(n0 + ln) * HH + lane]);
    float b0 = bnp[lane], b1 = bnp[64 + lane];
    float acc0[8], acc1[8];
#pragma unroll
    for (int ln = 0; ln < 8; ++ln) { acc0[ln] = b0; acc1[ln] = b1; }
#pragma unroll 8
    for (int k = 0; k < HH; ++k) {
        float w0 = Wnp[k * EMBD + lane];
        float w1 = Wnp[k * EMBD + 64 + lane];
#pragma unroll
        for (int ln = 0; ln < 8; ++ln) {
            float hv = bcast(hval[ln], k);
            acc0[ln] = fmaf(hv, w0, acc0[ln]);
            acc1[ln] = fmaf(hv, w1, acc1[ln]);
        }
    }
    if (*flag) {
        float* o = (float*)out + EMBD;
#pragma unroll
        for (int ln = 0; ln < 8; ++ln) {
            o[(long)(n0 + ln) * EMBD + lane] = acc0[ln];
            o[(long)(n0 + ln) * EMBD + 64 + lane] = acc1[ln];
        }
    } else {
        bf16* o = (bf16*)out + EMBD;
#pragma unroll
        for (int ln = 0; ln < 8; ++ln) {
            o[(long)(n0 + ln) * EMBD + lane] = __float2bfloat16(acc0[ln]);
            o[(long)(n0 + ln) * EMBD + 64 + lane] = __float2bfloat16(acc1[ln]);
        }
    }
}

extern "C" void kernel_launch(void* const* d_in, const int* in_sizes, int n_in,
                              void* d_out, int out_size, void* d_ws, size_t ws_size,
                              hipStream_t stream) {
    const int* eidx  = (const int*)d_in[1];
    const int* etype = (const int*)d_in[2];
    const int* src = eidx;
    const int* tgt = eidx + EE;

    int* flag = (int*)d_ws;
    float* base = (float*)d_ws + 16;

    const int fidx[17] = {0, 3, 4, 5, 6, 7, 8, 9, 10, 11, 12, 13, 14, 15, 16, 17, 18};
    ConvTab tab;
    float* conv[19];
    int cum = 0;
    for (int t = 0; t < 17; ++t) {
        int i = fidx[t];
        tab.in[t] = d_in[i];
        tab.n[t] = in_sizes[i];
        tab.cum[t] = cum;
        conv[i] = base + cum;
        cum += (in_sizes[i] + 15) & ~15;
    }
    tab.cum[17] = cum;

    k_detect<<<1, 64, 0, stream>>>(d_in[3], flag);
    k_convert_all<<<(cum + 255) / 256, 256, 0, stream>>>(tab, base, flag);

    float* p = base + cum;
    float* psum = p;  p += 256 * 64;
    float* pmax = p;  p += 256 * 64;
    int* count    = (int*)p;           p += NN;
    int* scanned  = (int*)p;           p += NN;
    int* partials = (int*)p;           p += 512;
    int* rank     = (int*)p;           p += EE;
    int* packed   = (int*)p;           p += EE;
    unsigned short* hbf0 = (unsigned short*)p;          // N*H bf16
    unsigned short* hbf1 = hbf0 + (size_t)NN * HH;
    unsigned short* Wc0  = hbf1 + (size_t)NN * HH;      // 64*320 bf16
    unsigned short* Wc1  = Wc0 + HH * 320;

    const float* nf      = conv[0];
    const float* Win     = conv[3];
    const float* bin     = conv[4];
    const float* Wself0  = conv[5];
    const float* bself0  = conv[6];
    const float* bases0  = conv[7];
    const float* coeffs0 = conv[8];
    const float* Wself1  = conv[9];
    const float* bself1  = conv[10];
    const float* bases1  = conv[11];
    const float* coeffs1 = conv[12];
    const float* Wr1     = conv[13];
    const float* br1     = conv[14];
    const float* Wr2     = conv[15];
    const float* br2     = conv[16];
    const float* Wnp     = conv[17];
    const float* bnp     = conv[18];

    const int NHB = (NN * HH) / 256;   // 25000
    const int SMB = NN / 32;           // 3125
    const int LYB = NN / 16;           // 6250
    const int EB  = (EE + 255) / 256;  // 3907

    // edge sort by target (shared by both layers)
    k_zero<<<(NN + 255) / 256, 256, 0, stream>>>(count, NN);
    k_hist<<<EB, 256, 0, stream>>>(tgt, count, rank);
    k_scan1<<<NP, 256, 0, stream>>>(count, scanned, partials);
    k_scan2<<<1, 512, 0, stream>>>(partials);
    k_scatter<<<EB, 256, 0, stream>>>(src, tgt, etype, rank, scanned, partials, packed);

    k_wcat<<<(HH * 320 + 255) / 256, 256, 0, stream>>>(bases0, Wself0, bases1, Wself1, Wc0, Wc1);
    k_input_proj<<<NHB, 256, 0, stream>>>(nf, Win, bin, hbf0);

    k_layer<<<LYB, 256, 0, stream>>>(hbf0, packed, scanned, partials, coeffs0, Wc0, bself0, hbf1);
    k_layer<<<LYB, 256, 0, stream>>>(hbf1, packed, scanned, partials, coeffs1, Wc1, bself1, hbf0);

    k_reduce<<<256, 256, 0, stream>>>(hbf0, psum, pmax);
    k_finish<<<1, 256, 0, stream>>>(psum, pmax, Wr1, br1, Wr2, br2, d_out, flag);
    k_node_emb2<<<SMB, 256, 0, stream>>>(hbf0, Wnp, bnp, d_out, flag);
}

// Round 8
// 507.406 us; speedup vs baseline: 5.7986x; 5.7986x over previous
//
#include <hip/hip_runtime.h>
#include <hip/hip_bf16.h>

#define NN 100000
#define EE 1000000
#define FIN 15
#define HH 64
#define EMBD 128
#define RR 13
#define NBASE 4
#define NP 391          // ceil(NN/256) scan blocks

typedef __hip_bfloat16 bf16;
typedef __attribute__((ext_vector_type(8))) short short8;   // MFMA A/B frag (8 bf16)
typedef __attribute__((ext_vector_type(4))) float f32x4;    // MFMA C/D frag

__device__ __forceinline__ float b2f(bf16 x) { return __bfloat162float(x); }
__device__ __forceinline__ float bcast(float v, int l) {
    return __uint_as_float(__builtin_amdgcn_readlane(__float_as_uint(v), l));
}
__device__ __forceinline__ int bcasti(int v, int l) {
    return (int)__builtin_amdgcn_readlane((unsigned)v, l);
}
__device__ __forceinline__ unsigned short f2bu(float f) {
    bf16 t = __float2bfloat16(f);
    return *reinterpret_cast<unsigned short*>(&t);
}
__device__ __forceinline__ float bu2f(unsigned u) {
    return __uint_as_float(u << 16);
}

// ---------- dtype auto-detect ----------
__global__ void k_detect(const void* __restrict__ win, int* __restrict__ flag) {
    int tid = threadIdx.x;
    const bf16* p = (const bf16*)win;
    int cnt = 0;
    for (int i = tid; i < FIN * HH; i += 64) {
        float v = b2f(p[i]);
        if (!(fabsf(v) < 0.3f)) cnt++;
    }
#pragma unroll
    for (int off = 32; off > 0; off >>= 1) cnt += __shfl_down(cnt, off, 64);
    if (tid == 0) *flag = (cnt > 40) ? 1 : 0;
}

// ---------- fused convert ----------
struct ConvTab {
    const void* in[17];
    int n[17];
    int cum[18];
};

__global__ void k_convert_all(ConvTab tab, float* __restrict__ base,
                              const int* __restrict__ flag) {
    int g = blockIdx.x * 256 + threadIdx.x;
    if (g >= tab.cum[17]) return;
    int t = 0;
#pragma unroll
    for (int i = 0; i < 17; ++i) if (g >= tab.cum[i + 1]) t = i + 1;
    int local = g - tab.cum[t];
    if (local >= tab.n[t]) return;
    float v;
    if (*flag) v = ((const float*)tab.in[t])[local];
    else       v = b2f(((const bf16*)tab.in[t])[local]);
    base[g] = v;
}

// ---------- edge counting-sort by target ----------
__global__ void k_zero(int* __restrict__ a, int n) {
    int i = blockIdx.x * 256 + threadIdx.x;
    if (i < n) a[i] = 0;
}

__global__ void k_hist(const int* __restrict__ tgt, int* __restrict__ count,
                       int* __restrict__ rank) {
    int e = blockIdx.x * 256 + threadIdx.x;
    if (e >= EE) return;
    rank[e] = atomicAdd(&count[tgt[e]], 1);
}

__global__ void k_scan1(const int* __restrict__ count, int* __restrict__ scanned,
                        int* __restrict__ partials) {
    __shared__ int buf[256];
    int tid = threadIdx.x;
    int i = blockIdx.x * 256 + tid;
    int v = (i < NN) ? count[i] : 0;
    buf[tid] = v;
    __syncthreads();
    for (int off = 1; off < 256; off <<= 1) {
        int t = (tid >= off) ? buf[tid - off] : 0;
        __syncthreads();
        buf[tid] += t;
        __syncthreads();
    }
    if (i < NN) scanned[i] = buf[tid] - v;
    if (tid == 255) partials[blockIdx.x] = buf[255];
}

__global__ void k_scan2(int* __restrict__ partials) {
    __shared__ int buf[512];
    int tid = threadIdx.x;
    int v = (tid < NP) ? partials[tid] : 0;
    buf[tid] = v;
    __syncthreads();
    for (int off = 1; off < 512; off <<= 1) {
        int t = (tid >= off) ? buf[tid - off] : 0;
        __syncthreads();
        buf[tid] += t;
        __syncthreads();
    }
    if (tid < NP) partials[tid] = buf[tid] - v;
}

// packed word: src(17) | etype(4)<<17
__global__ void k_scatter(const int* __restrict__ src, const int* __restrict__ tgt,
                          const int* __restrict__ et, const int* __restrict__ rank,
                          const int* __restrict__ scanned, const int* __restrict__ partials,
                          int* __restrict__ packed) {
    int e = blockIdx.x * 256 + threadIdx.x;
    if (e >= EE) return;
    int t = tgt[e];
    int pos = scanned[t] + partials[t >> 8] + rank[e];
    packed[pos] = src[e] | (et[e] << 17);
}

// WcatT[n][k] bf16, k 0..255: bases[k>>6][k&63][n]; k 256..319: Wself[k-256][n]
__global__ void k_wcat(const float* __restrict__ bases0, const float* __restrict__ Wself0,
                       const float* __restrict__ bases1, const float* __restrict__ Wself1,
                       unsigned short* __restrict__ W0, unsigned short* __restrict__ W1) {
    int idx = blockIdx.x * 256 + threadIdx.x;
    if (idx >= HH * 320) return;
    int n = idx / 320, k = idx - n * 320;
    int b = k >> 6, kk = k & 63;
    float v0 = (b < 4) ? bases0[b * 4096 + kk * 64 + n] : Wself0[kk * 64 + n];
    float v1 = (b < 4) ? bases1[b * 4096 + kk * 64 + n] : Wself1[kk * 64 + n];
    W0[idx] = f2bu(v0);
    W1[idx] = f2bu(v1);
}

// ---------- pipeline (bf16 node state) ----------

__global__ void k_input_proj(const float* __restrict__ nf, const float* __restrict__ Win,
                             const float* __restrict__ bin, unsigned short* __restrict__ h) {
    __shared__ float w[FIN * HH];
    __shared__ float bb[HH];
    int tid = threadIdx.x;
    for (int i = tid; i < FIN * HH; i += 256) w[i] = Win[i];
    if (tid < HH) bb[tid] = bin[tid];
    __syncthreads();
    int idx = blockIdx.x * 256 + tid;
    if (idx >= NN * HH) return;
    int n = idx >> 6, j = idx & 63;
    float acc = bb[j];
    const float* row = nf + n * FIN;
#pragma unroll
    for (int k = 0; k < FIN; ++k) acc = fmaf(row[k], w[k * HH + j], acc);
    h[idx] = f2bu(acc);
}

// Fused RGCN layer, 16 nodes/block:
//  phase 1 (register gather, NO atomics): wave wv owns nodes t0+4wv..+3;
//     S[ln][b] += coeffs[r_e][b] * h[src_e][lane]  (readlane-broadcast edge loop)
//     then plain bf16 ds_write into Sb[16][264]
//  phase 2 (MFMA, layout verified in r7): out = relu([S|h] @ WcatT^T + bself)
__global__ void __launch_bounds__(256, 4)
k_layer(const unsigned short* __restrict__ hin, const int* __restrict__ packed,
        const int* __restrict__ count, const int* __restrict__ scanned,
        const int* __restrict__ partials, const float* __restrict__ coeffs,
        const unsigned short* __restrict__ Wc, const float* __restrict__ bself,
        unsigned short* __restrict__ hout) {
    __shared__ __align__(16) unsigned short Sb[16 * 264];   // row stride 264 (16B-aligned)
    int tid = threadIdx.x;
    int lane = tid & 63;
    int wv = tid >> 6;
    int t0 = blockIdx.x * 16;

    // phase 1: register gather
    float S[4][NBASE];
#pragma unroll
    for (int ln = 0; ln < 4; ++ln)
        S[ln][0] = S[ln][1] = S[ln][2] = S[ln][3] = 0.f;

#pragma unroll
    for (int ln = 0; ln < 4; ++ln) {
        int t = t0 + wv * 4 + ln;
        int cnt = count[t];
        int s0 = scanned[t] + partials[t >> 8];
        for (int base = 0; base < cnt; base += 64) {
            int pk = 0;
            if (base + lane < cnt) pk = packed[s0 + base + lane];
            int m = min(64, cnt - base);
            for (int j = 0; j < m; ++j) {
                int v = bcasti(pk, j);
                int s = v & 0x1FFFF;
                int r = (v >> 17) & 0xF;
                float hh = bu2f((unsigned)hin[s * HH + lane]);  // coalesced 128 B, L2-hot
                float4 c = *(const float4*)(coeffs + r * NBASE);
                S[ln][0] = fmaf(c.x, hh, S[ln][0]);
                S[ln][1] = fmaf(c.y, hh, S[ln][1]);
                S[ln][2] = fmaf(c.z, hh, S[ln][2]);
                S[ln][3] = fmaf(c.w, hh, S[ln][3]);
            }
        }
    }
    // write S to LDS bf16: row = local node, k = b*64+lane  (stride-1 across lanes)
#pragma unroll
    for (int ln = 0; ln < 4; ++ln)
#pragma unroll
        for (int b = 0; b < NBASE; ++b)
            Sb[(wv * 4 + ln) * 264 + b * 64 + lane] = f2bu(S[ln][b]);
    __syncthreads();

    // phase 2: MFMA tail — wave wv computes 16 nodes x cols [16wv,16wv+16)
    int m16 = lane & 15;      // A: node row / B: output col
    int g = lane >> 4;        // k-group
    f32x4 acc = {0.f, 0.f, 0.f, 0.f};
    const unsigned short* brow = Wc + (wv * 16 + m16) * 320 + g * 8;
#pragma unroll
    for (int kb = 0; kb < 8; ++kb) {   // S part, K=256
        short8 a = *(const short8*)(&Sb[m16 * 264 + kb * 32 + g * 8]);
        short8 b = *(const short8*)(brow + kb * 32);
        acc = __builtin_amdgcn_mfma_f32_16x16x32_bf16(a, b, acc, 0, 0, 0);
    }
    const unsigned short* hrow = hin + (t0 + m16) * HH + g * 8;
#pragma unroll
    for (int kb = 0; kb < 2; ++kb) {   // self part, K=64
        short8 a = *(const short8*)(hrow + kb * 32);
        short8 b = *(const short8*)(brow + 256 + kb * 32);
        acc = __builtin_amdgcn_mfma_f32_16x16x32_bf16(a, b, acc, 0, 0, 0);
    }
    int col = wv * 16 + m16;
    float bias = bself[col];
#pragma unroll
    for (int r = 0; r < 4; ++r) {
        int row = g * 4 + r;
        hout[(t0 + row) * HH + col] = f2bu(fmaxf(acc[r] + bias, 0.f));
    }
}

// stage 1: per-block partial sum & max (h already relu'd)
__global__ void k_reduce(const unsigned short* __restrict__ h, float* __restrict__ psum,
                         float* __restrict__ pmax) {
    __shared__ float ls[256], lm[256];
    int tid = threadIdx.x;
    int j = tid & 63;
    int slot = tid >> 6;
    float s = 0.f, m = -1e30f;
    for (int n = blockIdx.x * 4 + slot; n < NN; n += gridDim.x * 4) {
        float v = bu2f((unsigned)h[n * HH + j]);
        s += v;
        m = fmaxf(m, v);
    }
    ls[tid] = s; lm[tid] = m;
    __syncthreads();
    if (tid < 64) {
        s = ls[tid] + ls[tid + 64] + ls[tid + 128] + ls[tid + 192];
        m = fmaxf(fmaxf(lm[tid], lm[tid + 64]), fmaxf(lm[tid + 128], lm[tid + 192]));
        psum[blockIdx.x * 64 + tid] = s;
        pmax[blockIdx.x * 64 + tid] = m;
    }
}

// stage 2 + readout MLP fused
__global__ void k_finish(const float* __restrict__ psum, const float* __restrict__ pmax,
                         const float* __restrict__ Wr1, const float* __restrict__ br1,
                         const float* __restrict__ Wr2, const float* __restrict__ br2,
                         void* __restrict__ out, const int* __restrict__ flag) {
    __shared__ float ls[256], lm[256];
    __shared__ float g[2 * HH];
    __shared__ float tbuf[HH];
    int tid = threadIdx.x;
    int j = tid & 63;
    int slot = tid >> 6;
    float s = 0.f, m = -1e30f;
    for (int i = slot; i < 256; i += 4) {
        s += psum[i * 64 + j];
        m = fmaxf(m, pmax[i * 64 + j]);
    }
    ls[tid] = s; lm[tid] = m;
    __syncthreads();
    if (tid < 64) {
        s = ls[tid] + ls[tid + 64] + ls[tid + 128] + ls[tid + 192];
        m = fmaxf(fmaxf(lm[tid], lm[tid + 64]), fmaxf(lm[tid + 128], lm[tid + 192]));
        g[tid] = s * (1.0f / NN);
        g[64 + tid] = m;
    }
    __syncthreads();
    if (tid < 64) {
        float acc = br1[tid];
#pragma unroll 8
        for (int k = 0; k < 2 * HH; ++k) acc = fmaf(g[k], Wr1[k * HH + tid], acc);
        tbuf[tid] = fmaxf(acc, 0.f);
    }
    __syncthreads();
    if (tid < EMBD) {
        float acc = br2[tid];
#pragma unroll 8
        for (int k = 0; k < HH; ++k) acc = fmaf(tbuf[k], Wr2[k * EMBD + tid], acc);
        if (*flag) ((float*)out)[tid] = acc;
        else       ((bf16*)out)[tid] = __float2bfloat16(acc);
    }
}

// node_emb: 8 nodes/wave, 128 cols (2/lane)
__global__ void k_node_emb2(const unsigned short* __restrict__ h, const float* __restrict__ Wnp,
                            const float* __restrict__ bnp, void* __restrict__ out,
                            const int* __restrict__ flag) {
    int tid = threadIdx.x;
    int lane = tid & 63;
    int wv = tid >> 6;
    int n0 = blockIdx.x * 32 + wv * 8;
    float hval[8];
#pragma unroll
    for (int ln = 0; ln < 8; ++ln)
        hval[ln] = bu2f((unsigned)h[(n0 + ln) * HH + lane]);
    float b0 = bnp[lane], b1 = bnp[64 + lane];
    float acc0[8], acc1[8];
#pragma unroll
    for (int ln = 0; ln < 8; ++ln) { acc0[ln] = b0; acc1[ln] = b1; }
#pragma unroll 8
    for (int k = 0; k < HH; ++k) {
        float w0 = Wnp[k * EMBD + lane];
        float w1 = Wnp[k * EMBD + 64 + lane];
#pragma unroll
        for (int ln = 0; ln < 8; ++ln) {
            float hv = bcast(hval[ln], k);
            acc0[ln] = fmaf(hv, w0, acc0[ln]);
            acc1[ln] = fmaf(hv, w1, acc1[ln]);
        }
    }
    if (*flag) {
        float* o = (float*)out + EMBD;
#pragma unroll
        for (int ln = 0; ln < 8; ++ln) {
            o[(long)(n0 + ln) * EMBD + lane] = acc0[ln];
            o[(long)(n0 + ln) * EMBD + 64 + lane] = acc1[ln];
        }
    } else {
        bf16* o = (bf16*)out + EMBD;
#pragma unroll
        for (int ln = 0; ln < 8; ++ln) {
            o[(long)(n0 + ln) * EMBD + lane] = __float2bfloat16(acc0[ln]);
            o[(long)(n0 + ln) * EMBD + 64 + lane] = __float2bfloat16(acc1[ln]);
        }
    }
}

extern "C" void kernel_launch(void* const* d_in, const int* in_sizes, int n_in,
                              void* d_out, int out_size, void* d_ws, size_t ws_size,
                              hipStream_t stream) {
    const int* eidx  = (const int*)d_in[1];
    const int* etype = (const int*)d_in[2];
    const int* src = eidx;
    const int* tgt = eidx + EE;

    int* flag = (int*)d_ws;
    float* base = (float*)d_ws + 16;

    const int fidx[17] = {0, 3, 4, 5, 6, 7, 8, 9, 10, 11, 12, 13, 14, 15, 16, 17, 18};
    ConvTab tab;
    float* conv[19];
    int cum = 0;
    for (int t = 0; t < 17; ++t) {
        int i = fidx[t];
        tab.in[t] = d_in[i];
        tab.n[t] = in_sizes[i];
        tab.cum[t] = cum;
        conv[i] = base + cum;
        cum += (in_sizes[i] + 15) & ~15;
    }
    tab.cum[17] = cum;

    k_detect<<<1, 64, 0, stream>>>(d_in[3], flag);
    k_convert_all<<<(cum + 255) / 256, 256, 0, stream>>>(tab, base, flag);

    float* p = base + cum;
    float* psum = p;  p += 256 * 64;
    float* pmax = p;  p += 256 * 64;
    int* count    = (int*)p;           p += NN;
    int* scanned  = (int*)p;           p += NN;
    int* partials = (int*)p;           p += 512;
    int* rank     = (int*)p;           p += EE;
    int* packed   = (int*)p;           p += EE;
    unsigned short* hbf0 = (unsigned short*)p;          // N*H bf16
    unsigned short* hbf1 = hbf0 + (size_t)NN * HH;
    unsigned short* Wc0  = hbf1 + (size_t)NN * HH;      // 64*320 bf16
    unsigned short* Wc1  = Wc0 + HH * 320;

    const float* nf      = conv[0];
    const float* Win     = conv[3];
    const float* bin     = conv[4];
    const float* Wself0  = conv[5];
    const float* bself0  = conv[6];
    const float* bases0  = conv[7];
    const float* coeffs0 = conv[8];
    const float* Wself1  = conv[9];
    const float* bself1  = conv[10];
    const float* bases1  = conv[11];
    const float* coeffs1 = conv[12];
    const float* Wr1     = conv[13];
    const float* br1     = conv[14];
    const float* Wr2     = conv[15];
    const float* br2     = conv[16];
    const float* Wnp     = conv[17];
    const float* bnp     = conv[18];

    const int NHB = (NN * HH) / 256;   // 25000
    const int SMB = NN / 32;           // 3125
    const int LYB = NN / 16;           // 6250
    const int EB  = (EE + 255) / 256;  // 3907

    // edge sort by target (shared by both layers)
    k_zero<<<(NN + 255) / 256, 256, 0, stream>>>(count, NN);
    k_hist<<<EB, 256, 0, stream>>>(tgt, count, rank);
    k_scan1<<<NP, 256, 0, stream>>>(count, scanned, partials);
    k_scan2<<<1, 512, 0, stream>>>(partials);
    k_scatter<<<EB, 256, 0, stream>>>(src, tgt, etype, rank, scanned, partials, packed);

    k_wcat<<<(HH * 320 + 255) / 256, 256, 0, stream>>>(bases0, Wself0, bases1, Wself1, Wc0, Wc1);
    k_input_proj<<<NHB, 256, 0, stream>>>(nf, Win, bin, hbf0);

    k_layer<<<LYB, 256, 0, stream>>>(hbf0, packed, count, scanned, partials, coeffs0, Wc0, bself0, hbf1);
    k_layer<<<LYB, 256, 0, stream>>>(hbf1, packed, count, scanned, partials, coeffs1, Wc1, bself1, hbf0);

    k_reduce<<<256, 256, 0, stream>>>(hbf0, psum, pmax);
    k_finish<<<1, 256, 0, stream>>>(psum, pmax, Wr1, br1, Wr2, br2, d_out, flag);
    k_node_emb2<<<SMB, 256, 0, stream>>>(hbf0, Wnp, bnp, d_out, flag);
}